// Round 1
// baseline (415.025 us; speedup 1.0000x reference)
//
#include <hip/hip_runtime.h>
#include <hip/hip_bf16.h>

typedef unsigned short u16;
typedef __attribute__((ext_vector_type(8))) short bf16x8;   // 8 bf16 = 4 VGPRs
typedef __attribute__((ext_vector_type(4))) float f32x4;

#define EPSN 1e-9f

// ---------- helpers ----------

__device__ __forceinline__ u16 f2bf(float f) {
    union { float f; unsigned int u; } c; c.f = f;
    unsigned int u = c.u;
    unsigned int r = (u + 0x7FFFu + ((u >> 16) & 1u)) >> 16;   // RNE
    return (u16)r;
}

__device__ __forceinline__ void load16_to_lds(const void* g, void* l) {
    __builtin_amdgcn_global_load_lds(
        (const __attribute__((address_space(1))) void*)g,
        (__attribute__((address_space(3))) void*)l,
        16, 0, 0);
}

// ---------- K1: per-row L2 normalize + cast to bf16, X and W in ONE launch ----------
#define MAXQ 8
__global__ __launch_bounds__(256) void normalize_cast2(
    const float* __restrict__ X, const float* __restrict__ W,
    u16* __restrict__ XO, u16* __restrict__ WO, int ncols, int nxrows) {
    const int blk = blockIdx.x;
    const float* src; u16* dst; size_t row;
    if (blk < nxrows) { src = X; dst = XO; row = blk; }
    else              { src = W; dst = WO; row = blk - nxrows; }

    const float4* xr = (const float4*)(src + row * (size_t)ncols);
    const int nq = ncols >> 2;

    float4 v[MAXQ];
    float ss = 0.f;
    #pragma unroll
    for (int k = 0; k < MAXQ; ++k) {
        int i = threadIdx.x + k * 256;
        if (i < nq) {
            v[k] = xr[i];
            ss += v[k].x*v[k].x + v[k].y*v[k].y + v[k].z*v[k].z + v[k].w*v[k].w;
        }
    }
    #pragma unroll
    for (int o = 32; o > 0; o >>= 1) ss += __shfl_down(ss, o);

    __shared__ float red[4];
    __shared__ float scale_sh;
    const int lane = threadIdx.x & 63, wv = threadIdx.x >> 6;
    if (lane == 0) red[wv] = ss;
    __syncthreads();
    if (threadIdx.x == 0) {
        float t = red[0] + red[1] + red[2] + red[3];
        scale_sh = 1.f / (sqrtf(t) + EPSN);
    }
    __syncthreads();
    const float s = scale_sh;

    ushort4* yr = (ushort4*)(dst + row * (size_t)ncols);
    #pragma unroll
    for (int k = 0; k < MAXQ; ++k) {
        int i = threadIdx.x + k * 256;
        if (i < nq) {
            ushort4 o4;
            o4.x = f2bf(v[k].x * s); o4.y = f2bf(v[k].y * s);
            o4.z = f2bf(v[k].z * s); o4.w = f2bf(v[k].w * s);
            yr[i] = o4;
        }
    }
}

// ---------- K2: 256x256 8-phase bf16 MFMA GEMM (A[M,K] * B[N,K]^T) + fused epilogue ----------
// Structure = the verified 256^2 8-phase template (T2+T3+T4+T5):
//   512 thr = 8 waves (2m x 4n), per-wave output 128x64 via acc[8][4] of 16x16x32 MFMA.
//   LDS 128 KiB: per operand [2 dbuf][2 khalf][256 rows][32 cols] bf16; a staged
//   "half" = one khalf of one operand (16 KB, contiguous -> global_load_lds legal).
//   Staging order per tile: (A,k0)(B,k0)(A,k1)(B,k1); compute phases consume in the
//   SAME order ((k0,nL)(k0,nR)(k1,nL)(k1,nR)) so a counted vmcnt(4) twice per tile
//   keeps 4-8 loads in flight ACROSS barriers (never drains to 0 in the main loop).
//   Bank swizzle: chunk c of row r stored at slot c ^ ((r>>1)&3); applied on the
//   GLOBAL source address (LDS dest stays linear) and on the ds_read address.
__global__ __launch_bounds__(512, 2) void gemm_softhebb(
    const u16* __restrict__ A, const u16* __restrict__ B,
    const float* __restrict__ logprior, const float* __restrict__ lambp,
    float* __restrict__ Ul, float* __restrict__ rowsum,
    int M, int N, int K) {
    __shared__ __align__(16) u16 lA[32768];   // 64 KB
    __shared__ __align__(16) u16 lB[32768];   // 64 KB

    const int tid  = threadIdx.x;
    const int lane = tid & 63;
    const int wid  = tid >> 6;
    const int wm   = wid >> 2;     // 0..1
    const int wn   = wid & 3;      // 0..3

    // XCD-aware swizzle: each XCD gets a contiguous wg chunk; tile_n-per-XCD so the
    // 1 MB B-panel stays L2-resident while A streams through L3.
    const int nwg = gridDim.x;
    int wg = blockIdx.x;
    if ((nwg & 7) == 0) {
        const int cpx = nwg >> 3;
        wg = (wg & 7) * cpx + (wg >> 3);
    }
    const int ntm  = M >> 8;
    const int tn   = wg / ntm;
    const int tm   = wg - tn * ntm;
    const int row0 = tm << 8;
    const int col0 = tn << 8;

    // ---- staging setup: linear chunk n -> lds (r=n>>2, slot=n&3); global chunk
    //      c = slot ^ ((r>>1)&3)  (involution; read side applies the same XOR) ----
    const u16* gA[2]; const u16* gB[2]; int lo[2];
    #pragma unroll
    for (int p = 0; p < 2; ++p) {
        int n = p * 512 + tid;
        int r = n >> 2, slot = n & 3;
        int c = slot ^ ((r >> 1) & 3);
        gA[p] = A + (size_t)(row0 + r) * K + c * 8;
        gB[p] = B + (size_t)(col0 + r) * K + c * 8;
        lo[p] = n * 8;                     // u16 index inside a 16 KB half-block
    }

    // ---- fragment ds_read offsets (u16 index inside a half-block) ----
    // A-frag lane map (m89-verified): row = m*16 + (lane&15), k-chunk = lane>>4
    const int sl = ((lane >> 4) ^ ((lane >> 1) & 3)) * 8;
    int aoff[8], boff[4];
    #pragma unroll
    for (int i = 0; i < 8; ++i)
        aoff[i] = (wm * 128 + i * 16 + (lane & 15)) * 32 + sl;
    #pragma unroll
    for (int j = 0; j < 4; ++j)
        boff[j] = (wn * 64 + j * 16 + (lane & 15)) * 32 + sl;

    f32x4 acc[8][4] = {};
    bf16x8 af[8];

    const int nt = K >> 6;

    auto stage_half = [&](int buf, int which, int koff) {
        const int h  = which >> 1;
        const int go = koff + h * 32;
        u16* lb = ((which & 1) ? lB : lA) + buf * 16384 + h * 8192;
        if (which & 1) {
            load16_to_lds(gB[0] + go, lb + lo[0]);
            load16_to_lds(gB[1] + go, lb + lo[1]);
        } else {
            load16_to_lds(gA[0] + go, lb + lo[0]);
            load16_to_lds(gA[1] + go, lb + lo[1]);
        }
    };

    // prologue: stage tile 0 (8 loads), retire the k0 halves, keep k1 in flight
    stage_half(0, 0, 0); stage_half(0, 1, 0); stage_half(0, 2, 0); stage_half(0, 3, 0);
    asm volatile("s_waitcnt vmcnt(4)" ::: "memory");
    __builtin_amdgcn_s_barrier();

    for (int t = 0; t < nt; ++t) {
        const int cur = t & 1;
        // last tile re-stages tile 0 (never read) to keep vmcnt immediates uniform
        const int nk  = (t + 1 < nt) ? ((t + 1) << 6) : 0;
        const u16* pA = lA + cur * 16384;
        const u16* pB = lB + cur * 16384;

        #pragma unroll
        for (int h = 0; h < 2; ++h) {
            const u16* phA = pA + h * 8192;
            const u16* phB = pB + h * 8192;
            #pragma unroll
            for (int nh = 0; nh < 2; ++nh) {
                // ds-reads for this quadrant
                if (nh == 0) {
                    #pragma unroll
                    for (int i = 0; i < 8; ++i)
                        af[i] = *(const bf16x8*)(phA + aoff[i]);
                }
                bf16x8 b0 = *(const bf16x8*)(phB + boff[nh * 2 + 0]);
                bf16x8 b1 = *(const bf16x8*)(phB + boff[nh * 2 + 1]);
                // issue one half-tile prefetch of the next tile
                stage_half(cur ^ 1, h * 2 + nh, nk);
                __builtin_amdgcn_s_barrier();
                asm volatile("s_waitcnt lgkmcnt(0)" ::: "memory");
                __builtin_amdgcn_s_setprio(1);
                #pragma unroll
                for (int i = 0; i < 8; ++i) {
                    acc[i][nh*2+0] = __builtin_amdgcn_mfma_f32_16x16x32_bf16(
                        af[i], b0, acc[i][nh*2+0], 0, 0, 0);
                    acc[i][nh*2+1] = __builtin_amdgcn_mfma_f32_16x16x32_bf16(
                        af[i], b1, acc[i][nh*2+1], 0, 0, 0);
                }
                __builtin_amdgcn_s_setprio(0);
                // counted waits, twice per tile, never 0:
                //  nh==1,h==0: retire (A,k1)(B,k1) of THIS tile (needed next phase)
                //  nh==1,h==1: retire (A,k0)(B,k0) of NEXT tile (needed at boundary)
                if (nh == 1) asm volatile("s_waitcnt vmcnt(4)" ::: "memory");
                __builtin_amdgcn_s_barrier();
            }
        }
    }

    // epilogue: u = relu(a); ul = u^lam * exp(logprior); write + row partial sums
    // C/D layout: col = lane&15, row = (lane>>4)*4 + p   [m89/m91 verified]
    const float lam = *lambp;
    const bool lam4 = (lam == 4.0f);
    float el[4];
    #pragma unroll
    for (int j = 0; j < 4; ++j)
        el[j] = __expf(logprior[col0 + wn * 64 + j * 16 + (lane & 15)]);

    #pragma unroll
    for (int i = 0; i < 8; ++i) {
        #pragma unroll
        for (int p = 0; p < 4; ++p) {
            const int m = row0 + wm * 128 + i * 16 + (lane >> 4) * 4 + p;
            float* outrow = Ul + (size_t)m * N + col0 + wn * 64 + (lane & 15);
            float rs = 0.f;
            #pragma unroll
            for (int j = 0; j < 4; ++j) {
                float a = acc[i][j][p];
                float u = 0.f;
                if (a > 0.f) {
                    float pw;
                    if (lam4) { float a2 = a * a; pw = a2 * a2; }
                    else      { pw = __powf(a, lam); }
                    u = pw * el[j];
                }
                outrow[j * 16] = u;
                rs += u;
            }
            rs += __shfl_xor(rs, 1);
            rs += __shfl_xor(rs, 2);
            rs += __shfl_xor(rs, 4);
            rs += __shfl_xor(rs, 8);
            if ((lane & 15) == 0) atomicAdd(&rowsum[m], rs);
        }
    }
}

// ---------- K3: y = ul / (rowsum + eps), one block per row ----------
__global__ __launch_bounds__(256) void finalize_row(
    float* __restrict__ Ul, const float* __restrict__ rowsum, int nq) {
    const size_t row = blockIdx.x;
    const float inv = 1.f / (rowsum[row] + EPSN);
    float4* p = (float4*)(Ul + row * (size_t)nq * 4);
    for (int i = threadIdx.x; i < nq; i += 256) {
        float4 v = p[i];
        v.x *= inv; v.y *= inv; v.z *= inv; v.w *= inv;
        p[i] = v;
    }
}

// ---------- launch ----------
static inline size_t align256(size_t x) { return (x + 255) & ~(size_t)255; }

extern "C" void kernel_launch(void* const* d_in, const int* in_sizes, int n_in,
                              void* d_out, int out_size, void* d_ws, size_t ws_size,
                              hipStream_t stream) {
    const float* x        = (const float*)d_in[0];
    const float* w        = (const float*)d_in[1];
    const float* logprior = (const float*)d_in[2];
    const float* lamb     = (const float*)d_in[3];
    const int OUT = in_sizes[2];                // 2048
    const int IN  = in_sizes[1] / OUT;          // 2048
    const int B   = in_sizes[0] / IN;           // 16384
    float* out = (float*)d_out;

    char* ws = (char*)d_ws;
    size_t off = 0;
    u16* xn = (u16*)(ws + off);        off += align256((size_t)B * IN * sizeof(u16));
    u16* wn = (u16*)(ws + off);        off += align256((size_t)OUT * IN * sizeof(u16));
    float* rowsum = (float*)(ws + off); off += align256((size_t)B * sizeof(float));

    hipMemsetAsync(rowsum, 0, (size_t)B * sizeof(float), stream);
    normalize_cast2<<<B + OUT, 256, 0, stream>>>(x, w, xn, wn, IN, B);

    const int nblk = (B / 256) * (OUT / 256);   // 512
    gemm_softhebb<<<nblk, 512, 0, stream>>>(xn, wn, logprior, lamb, out, rowsum, B, OUT, IN);

    finalize_row<<<B, 256, 0, stream>>>(out, rowsum, OUT / 4);
}